// Round 1
// baseline (244.963 us; speedup 1.0000x reference)
//
#include <hip/hip_runtime.h>
#include <hip/hip_bf16.h>
#include <stdint.h>

typedef __attribute__((ext_vector_type(8))) short short8;
typedef __attribute__((ext_vector_type(4))) float f32x4;

#define BIGF 1e9f

__device__ inline float b2f(unsigned short u) {
    union { unsigned int i; float f; } v; v.i = ((unsigned int)u) << 16; return v.f;
}

// ---------------------------------------------------------------------------
// Kernel 1: L2-normalize each row (fp32 math, matching reference), emit bf16
// normalized embeddings + gpid[j] = genuine_j ? pid_j : -1.
// One block (256 threads) per row; D == 256.
// ---------------------------------------------------------------------------
__global__ __launch_bounds__(256) void k_normalize(
    const float* __restrict__ emb, const int* __restrict__ labels,
    const int* __restrict__ pids, unsigned short* __restrict__ normed,
    int* __restrict__ gpid, int D)
{
    int row = blockIdx.x;
    int t = threadIdx.x;
    float x = emb[(size_t)row * D + t];
    float ss = x * x;
    #pragma unroll
    for (int off = 32; off >= 1; off >>= 1) ss += __shfl_xor(ss, off, 64);
    __shared__ float red[4];
    int wave = t >> 6, lane = t & 63;
    if (lane == 0) red[wave] = ss;
    __syncthreads();
    float total = red[0] + red[1] + red[2] + red[3];
    float norm = fmaxf(sqrtf(total), 1e-12f);
    float v = x / norm;
    __hip_bfloat16 h = __float2bfloat16(v);
    normed[(size_t)row * D + t] = *reinterpret_cast<unsigned short*>(&h);
    if (t == 0) gpid[row] = (labels[row] == 1) ? pids[row] : -1;
}

// ---------------------------------------------------------------------------
// Kernel 2: hardest positive per anchor. hp[i] = min sim over {same pid,
// genuine, j != i}; BIGF if none (encodes pos_any). One wave per anchor;
// ballot-scan pid matches, wave-cooperative dot per match.
// ---------------------------------------------------------------------------
__global__ __launch_bounds__(256) void k_hp(
    const unsigned short* __restrict__ normed, const int* __restrict__ labels,
    const int* __restrict__ pids, float* __restrict__ hp_out, int N, int D)
{
    int w = threadIdx.x >> 6, lane = threadIdx.x & 63;
    int i = blockIdx.x * 4 + w;
    // anchor fragment: lane holds k = lane*4 .. lane*4+3
    const unsigned short* rowi = normed + (size_t)i * D + lane * 4;
    uint2 ai = *reinterpret_cast<const uint2*>(rowi);
    float a0 = b2f((unsigned short)(ai.x & 0xffffu));
    float a1 = b2f((unsigned short)(ai.x >> 16));
    float a2 = b2f((unsigned short)(ai.y & 0xffffu));
    float a3 = b2f((unsigned short)(ai.y >> 16));
    int mypid = pids[i];
    float hmin = BIGF;
    for (int base = 0; base < N; base += 64) {
        int j = base + lane;
        bool m = (pids[j] == mypid) && (labels[j] == 1) && (j != i);
        unsigned long long mask = __ballot(m);
        while (mask) {
            int b = __ffsll(mask) - 1;
            mask &= mask - 1;
            int jj = base + b;
            const unsigned short* rowj = normed + (size_t)jj * D + lane * 4;
            uint2 bj = *reinterpret_cast<const uint2*>(rowj);
            float s = a0 * b2f((unsigned short)(bj.x & 0xffffu))
                    + a1 * b2f((unsigned short)(bj.x >> 16))
                    + a2 * b2f((unsigned short)(bj.y & 0xffffu))
                    + a3 * b2f((unsigned short)(bj.y >> 16));
            #pragma unroll
            for (int off = 32; off >= 1; off >>= 1) s += __shfl_xor(s, off, 64);
            hmin = fminf(hmin, s);
        }
    }
    if (lane == 0) hp_out[i] = hmin;
}

// ---------------------------------------------------------------------------
// Kernel 3: the big pass. For each anchor row, streaming MFMA over all
// columns, maintaining per-row: hn_all = max sim over negatives, and
// mbel = max sim over negatives strictly below hp. Masks applied in the
// epilogue per 16x16x32 MFMA C-tile (col=lane&15, row=quad*4+reg).
// Block: 256 thr = 4 waves in 2x2 (wr: 2x32 rows, wc: 2x64 cols).
// Block tile 64 rows x 128 cols/iter; grid (N/64, 4) col-splits.
// A-fragments register-resident (full K=256). Partial maxima -> ws slots.
// ---------------------------------------------------------------------------
__global__ __launch_bounds__(256) void k_pass2(
    const unsigned short* __restrict__ normed, const int* __restrict__ pids,
    const int* __restrict__ gpid, const float* __restrict__ hp,
    float* __restrict__ p_hnall, float* __restrict__ p_mbel, int N, int D)
{
    const int lane = threadIdx.x & 63;
    const int w = threadIdx.x >> 6;
    const int wr = w & 1, wc = w >> 1;
    const int quad = lane >> 4, l16 = lane & 15;
    const int rbase = blockIdx.x * 64 + wr * 32;
    const int colspan = N >> 2;            // grid.y == 4
    const int cstart = blockIdx.y * colspan;

    // A fragments: A[m=l16][k=quad*8+t], k-block kb covers k = kb*32..+31
    short8 afrag[2][8];
    #pragma unroll
    for (int mb = 0; mb < 2; ++mb) {
        const unsigned short* ap =
            normed + (size_t)(rbase + mb * 16 + l16) * D + quad * 8;
        #pragma unroll
        for (int kb = 0; kb < 8; ++kb)
            afrag[mb][kb] = *reinterpret_cast<const short8*>(ap + kb * 32);
    }
    int pid_r[2][4]; float hp_r[2][4];
    #pragma unroll
    for (int mb = 0; mb < 2; ++mb) {
        #pragma unroll
        for (int r = 0; r < 4; ++r) {
            int rr = rbase + mb * 16 + quad * 4 + r;
            pid_r[mb][r] = pids[rr];
            hp_r[mb][r] = hp[rr];
        }
    }
    float hnall[2][4], mbel[2][4];
    #pragma unroll
    for (int mb = 0; mb < 2; ++mb)
        #pragma unroll
        for (int r = 0; r < 4; ++r) { hnall[mb][r] = -BIGF; mbel[mb][r] = -BIGF; }

    for (int ct = 0; ct < colspan; ct += 128) {
        int cbase = cstart + ct + wc * 64;
        int gp[4];
        const unsigned short* bp[4];
        #pragma unroll
        for (int nb = 0; nb < 4; ++nb) {
            int col = cbase + nb * 16 + l16;
            gp[nb] = gpid[col];
            bp[nb] = normed + (size_t)col * D + quad * 8;
        }
        f32x4 acc[2][4];
        #pragma unroll
        for (int mb = 0; mb < 2; ++mb)
            #pragma unroll
            for (int nb = 0; nb < 4; ++nb)
                acc[mb][nb] = (f32x4){0.f, 0.f, 0.f, 0.f};
        #pragma unroll
        for (int kb = 0; kb < 8; ++kb) {
            short8 b[4];
            #pragma unroll
            for (int nb = 0; nb < 4; ++nb)
                b[nb] = *reinterpret_cast<const short8*>(bp[nb] + kb * 32);
            #pragma unroll
            for (int mb = 0; mb < 2; ++mb)
                #pragma unroll
                for (int nb = 0; nb < 4; ++nb)
                    acc[mb][nb] = __builtin_amdgcn_mfma_f32_16x16x32_bf16(
                        afrag[mb][kb], b[nb], acc[mb][nb], 0, 0, 0);
        }
        // epilogue: 6 VALU ops per element, overlapped with MFMA pipe
        #pragma unroll
        for (int mb = 0; mb < 2; ++mb)
            #pragma unroll
            for (int nb = 0; nb < 4; ++nb)
                #pragma unroll
                for (int r = 0; r < 4; ++r) {
                    float s = acc[mb][nb][r];
                    float t = (pid_r[mb][r] != gp[nb]) ? s : -BIGF;
                    hnall[mb][r] = fmaxf(hnall[mb][r], t);
                    float t2 = (t < hp_r[mb][r]) ? t : -BIGF;
                    mbel[mb][r] = fmaxf(mbel[mb][r], t2);
                }
    }
    // reduce across the 16 lanes holding the same row (xor 1,2,4,8 stays
    // within the quad's 16-lane group), then write one partial per row/slot
    int slot = blockIdx.y * 2 + wc;      // 8 slots per row
    #pragma unroll
    for (int mb = 0; mb < 2; ++mb) {
        #pragma unroll
        for (int r = 0; r < 4; ++r) {
            float v1 = hnall[mb][r], v2 = mbel[mb][r];
            #pragma unroll
            for (int off = 8; off >= 1; off >>= 1) {
                v1 = fmaxf(v1, __shfl_xor(v1, off, 64));
                v2 = fmaxf(v2, __shfl_xor(v2, off, 64));
            }
            if (l16 == 0) {
                int rr = rbase + mb * 16 + quad * 4 + r;
                p_hnall[rr * 8 + slot] = v1;
                p_mbel[rr * 8 + slot] = v2;
            }
        }
    }
}

// ---------------------------------------------------------------------------
// Kernel 4: per-row loss + per-block sums. One thread per row, 32 blocks.
// hn = (mbel > hp - margin) ? mbel : hn_all   (hn_cand == hn_all identity)
// ---------------------------------------------------------------------------
__global__ __launch_bounds__(256) void k_rowloss(
    const float* __restrict__ hp, const float* __restrict__ p_hnall,
    const float* __restrict__ p_mbel, const int* __restrict__ labels,
    float* __restrict__ bsum, float* __restrict__ bcnt)
{
    int i = blockIdx.x * blockDim.x + threadIdx.x;
    float hn_all = -BIGF, mb = -BIGF;
    #pragma unroll
    for (int s = 0; s < 8; ++s) {
        hn_all = fmaxf(hn_all, p_hnall[i * 8 + s]);
        mb = fmaxf(mb, p_mbel[i * 8 + s]);
    }
    float hpv = hp[i];
    bool valid = (labels[i] == 1) && (hpv < 1e8f) && (hn_all > -1e8f);
    float hn = (mb > hpv - 0.5f) ? mb : hn_all;
    float base = fmaxf(hn - hpv + 0.5f, 0.f);
    float wgt = (hpv < 0.6f || hn > 0.3f) ? 2.f : 1.f;
    float loss = base * wgt + 0.5f * (1.f - hpv) + 0.5f * fmaxf(hn + 0.2f, 0.f);
    float lsum = valid ? loss : 0.f;
    float lcnt = valid ? 1.f : 0.f;
    #pragma unroll
    for (int off = 32; off >= 1; off >>= 1) {
        lsum += __shfl_xor(lsum, off, 64);
        lcnt += __shfl_xor(lcnt, off, 64);
    }
    __shared__ float rs[4], rc[4];
    int wv = threadIdx.x >> 6, lane = threadIdx.x & 63;
    if (lane == 0) { rs[wv] = lsum; rc[wv] = lcnt; }
    __syncthreads();
    if (threadIdx.x == 0) {
        bsum[blockIdx.x] = rs[0] + rs[1] + rs[2] + rs[3];
        bcnt[blockIdx.x] = rc[0] + rc[1] + rc[2] + rc[3];
    }
}

// ---------------------------------------------------------------------------
// Kernel 5: final scalar. nb <= 64 partials.
// ---------------------------------------------------------------------------
__global__ __launch_bounds__(64) void k_final(
    const float* __restrict__ bsum, const float* __restrict__ bcnt,
    float* __restrict__ out, int nb)
{
    int t = threadIdx.x;
    float s = 0.f, c = 0.f;
    if (t < nb) { s = bsum[t]; c = bcnt[t]; }
    #pragma unroll
    for (int off = 32; off >= 1; off >>= 1) {
        s += __shfl_xor(s, off, 64);
        c += __shfl_xor(c, off, 64);
    }
    if (t == 0) out[0] = (c > 0.f) ? s / fmaxf(c, 1.f) : 0.f;
}

extern "C" void kernel_launch(void* const* d_in, const int* in_sizes, int n_in,
                              void* d_out, int out_size, void* d_ws, size_t ws_size,
                              hipStream_t stream)
{
    const float* emb = (const float*)d_in[0];
    const int* labels = (const int*)d_in[1];
    const int* pids = (const int*)d_in[2];
    float* out = (float*)d_out;
    int N = in_sizes[1];          // 8192
    int D = in_sizes[0] / N;      // 256

    char* ws = (char*)d_ws;
    unsigned short* normed = (unsigned short*)ws;  ws += (size_t)N * D * 2;  // 4 MB bf16
    int* gpid = (int*)ws;                          ws += (size_t)N * 4;
    float* hp = (float*)ws;                        ws += (size_t)N * 4;
    float* p_hnall = (float*)ws;                   ws += (size_t)N * 8 * 4;
    float* p_mbel = (float*)ws;                    ws += (size_t)N * 8 * 4;
    float* bsum = (float*)ws;                      ws += 64 * 4;
    float* bcnt = (float*)ws;                      ws += 64 * 4;

    k_normalize<<<N, D, 0, stream>>>(emb, labels, pids, normed, gpid, D);
    k_hp<<<N / 4, 256, 0, stream>>>(normed, labels, pids, hp, N, D);
    k_pass2<<<dim3(N / 64, 4), 256, 0, stream>>>(normed, pids, gpid, hp,
                                                 p_hnall, p_mbel, N, D);
    int rb = N / 256;  // 32
    k_rowloss<<<rb, 256, 0, stream>>>(hp, p_hnall, p_mbel, labels, bsum, bcnt);
    k_final<<<1, 64, 0, stream>>>(bsum, bcnt, out, rb);
}

// Round 2
// 239.602 us; speedup vs baseline: 1.0224x; 1.0224x over previous
//
#include <hip/hip_runtime.h>
#include <hip/hip_bf16.h>
#include <stdint.h>

typedef __attribute__((ext_vector_type(8))) short short8;
typedef __attribute__((ext_vector_type(4))) float f32x4;

#define BIGF 1e9f
#define COLSPLIT 16              // grid.y for k_pass2
#define NSLOT (COLSPLIT * 2)     // partial-max slots per row

__device__ inline float blo(unsigned int u) {
    union { unsigned int i; float f; } v; v.i = u << 16; return v.f;
}
__device__ inline float bhi(unsigned int u) {
    union { unsigned int i; float f; } v; v.i = u & 0xffff0000u; return v.f;
}

// ---------------------------------------------------------------------------
// Kernel 1: L2-normalize each row (fp32 math), emit bf16 normed + gpid,
// and init hp[row] = BIGF ("no positive" sentinel).
// ---------------------------------------------------------------------------
__global__ __launch_bounds__(256) void k_normalize(
    const float* __restrict__ emb, const int* __restrict__ labels,
    const int* __restrict__ pids, unsigned short* __restrict__ normed,
    int* __restrict__ gpid, float* __restrict__ hp_init, int D)
{
    int row = blockIdx.x;
    int t = threadIdx.x;
    float x = emb[(size_t)row * D + t];
    float ss = x * x;
    #pragma unroll
    for (int off = 32; off >= 1; off >>= 1) ss += __shfl_xor(ss, off, 64);
    __shared__ float red[4];
    int wave = t >> 6, lane = t & 63;
    if (lane == 0) red[wave] = ss;
    __syncthreads();
    float total = red[0] + red[1] + red[2] + red[3];
    float norm = fmaxf(sqrtf(total), 1e-12f);
    float v = x / norm;
    __hip_bfloat16 h = __float2bfloat16(v);
    normed[(size_t)row * D + t] = *reinterpret_cast<unsigned short*>(&h);
    if (t == 0) {
        gpid[row] = (labels[row] == 1) ? pids[row] : -1;
        hp_init[row] = BIGF;
    }
}

// ---------------------------------------------------------------------------
// Kernel 2: hardest positive via per-pid groups. One block per pid value.
// Gather genuine members (avg ~16), then one (i,j) pair per thread:
// 256-d bf16 dot in fp32, ordered-uint atomicMin in LDS for per-i minimum.
// ---------------------------------------------------------------------------
__global__ __launch_bounds__(256) void k_hp_pid(
    const unsigned short* __restrict__ normed, const int* __restrict__ labels,
    const int* __restrict__ pids, float* __restrict__ hp_out, int N, int D)
{
    __shared__ int list[512];
    __shared__ unsigned int hp_loc[512];
    __shared__ int cnt;
    int p = blockIdx.x;
    int t = threadIdx.x;
    if (t == 0) cnt = 0;
    __syncthreads();
    for (int j = t; j < N; j += 256)
        if (pids[j] == p && labels[j] == 1) {
            int idx = atomicAdd(&cnt, 1);
            if (idx < 512) list[idx] = j;
        }
    __syncthreads();
    int M = min(cnt, 512);
    for (int s = t; s < M; s += 256) hp_loc[s] = 0xFFFFFFFFu;
    __syncthreads();
    for (int pr = t; pr < M * M; pr += 256) {
        int i = pr / M, j = pr % M;
        if (i == j) continue;
        const uint4* ap = (const uint4*)(normed + (size_t)list[i] * D);
        const uint4* bp = (const uint4*)(normed + (size_t)list[j] * D);
        float s = 0.f;
        #pragma unroll 4
        for (int k = 0; k < D / 8; ++k) {
            uint4 a = ap[k], b = bp[k];
            s += blo(a.x) * blo(b.x) + bhi(a.x) * bhi(b.x);
            s += blo(a.y) * blo(b.y) + bhi(a.y) * bhi(b.y);
            s += blo(a.z) * blo(b.z) + bhi(a.z) * bhi(b.z);
            s += blo(a.w) * blo(b.w) + bhi(a.w) * bhi(b.w);
        }
        unsigned int bits = __float_as_uint(s);
        unsigned int key = (bits & 0x80000000u) ? ~bits : (bits | 0x80000000u);
        atomicMin(&hp_loc[i], key);
    }
    __syncthreads();
    for (int s = t; s < M; s += 256) {
        unsigned int key = hp_loc[s];
        float v;
        if (key == 0xFFFFFFFFu) v = BIGF;   // M==1: no positive partner
        else {
            unsigned int bits = (key & 0x80000000u) ? (key & 0x7fffffffu) : ~key;
            v = __uint_as_float(bits);
        }
        hp_out[list[s]] = v;
    }
}

// ---------------------------------------------------------------------------
// Kernel 3: streaming MFMA pass. Per anchor row: hn_all = max sim over
// negatives; mbel = max sim over negatives strictly below hp.
// Block: 4 waves 2x2 (64 rows x 128 cols/iter); grid (N/64, COLSPLIT).
// A-fragments register-resident (full K=256). Partial maxima -> ws slots.
// ---------------------------------------------------------------------------
__global__ __launch_bounds__(256) void k_pass2(
    const unsigned short* __restrict__ normed, const int* __restrict__ pids,
    const int* __restrict__ gpid, const float* __restrict__ hp,
    float* __restrict__ p_hnall, float* __restrict__ p_mbel, int N, int D)
{
    const int lane = threadIdx.x & 63;
    const int w = threadIdx.x >> 6;
    const int wr = w & 1, wc = w >> 1;
    const int quad = lane >> 4, l16 = lane & 15;
    const int rbase = blockIdx.x * 64 + wr * 32;
    const int colspan = N / COLSPLIT;
    const int cstart = blockIdx.y * colspan;

    short8 afrag[2][8];
    #pragma unroll
    for (int mb = 0; mb < 2; ++mb) {
        const unsigned short* ap =
            normed + (size_t)(rbase + mb * 16 + l16) * D + quad * 8;
        #pragma unroll
        for (int kb = 0; kb < 8; ++kb)
            afrag[mb][kb] = *reinterpret_cast<const short8*>(ap + kb * 32);
    }
    int pid_r[2][4]; float hp_r[2][4];
    #pragma unroll
    for (int mb = 0; mb < 2; ++mb) {
        #pragma unroll
        for (int r = 0; r < 4; ++r) {
            int rr = rbase + mb * 16 + quad * 4 + r;
            pid_r[mb][r] = pids[rr];
            hp_r[mb][r] = hp[rr];
        }
    }
    float hnall[2][4], mbel[2][4];
    #pragma unroll
    for (int mb = 0; mb < 2; ++mb)
        #pragma unroll
        for (int r = 0; r < 4; ++r) { hnall[mb][r] = -BIGF; mbel[mb][r] = -BIGF; }

    for (int ct = 0; ct < colspan; ct += 128) {
        int cbase = cstart + ct + wc * 64;
        int gp[4];
        const unsigned short* bp[4];
        #pragma unroll
        for (int nb = 0; nb < 4; ++nb) {
            int col = cbase + nb * 16 + l16;
            gp[nb] = gpid[col];
            bp[nb] = normed + (size_t)col * D + quad * 8;
        }
        f32x4 acc[2][4];
        #pragma unroll
        for (int mb = 0; mb < 2; ++mb)
            #pragma unroll
            for (int nb = 0; nb < 4; ++nb)
                acc[mb][nb] = (f32x4){0.f, 0.f, 0.f, 0.f};
        #pragma unroll
        for (int kb = 0; kb < 8; ++kb) {
            short8 b[4];
            #pragma unroll
            for (int nb = 0; nb < 4; ++nb)
                b[nb] = *reinterpret_cast<const short8*>(bp[nb] + kb * 32);
            #pragma unroll
            for (int mb = 0; mb < 2; ++mb)
                #pragma unroll
                for (int nb = 0; nb < 4; ++nb)
                    acc[mb][nb] = __builtin_amdgcn_mfma_f32_16x16x32_bf16(
                        afrag[mb][kb], b[nb], acc[mb][nb], 0, 0, 0);
        }
        #pragma unroll
        for (int mb = 0; mb < 2; ++mb)
            #pragma unroll
            for (int nb = 0; nb < 4; ++nb)
                #pragma unroll
                for (int r = 0; r < 4; ++r) {
                    float s = acc[mb][nb][r];
                    float t = (pid_r[mb][r] != gp[nb]) ? s : -BIGF;
                    hnall[mb][r] = fmaxf(hnall[mb][r], t);
                    float t2 = (t < hp_r[mb][r]) ? t : -BIGF;
                    mbel[mb][r] = fmaxf(mbel[mb][r], t2);
                }
    }
    int slot = blockIdx.y * 2 + wc;      // NSLOT slots per row
    #pragma unroll
    for (int mb = 0; mb < 2; ++mb) {
        #pragma unroll
        for (int r = 0; r < 4; ++r) {
            float v1 = hnall[mb][r], v2 = mbel[mb][r];
            #pragma unroll
            for (int off = 8; off >= 1; off >>= 1) {
                v1 = fmaxf(v1, __shfl_xor(v1, off, 64));
                v2 = fmaxf(v2, __shfl_xor(v2, off, 64));
            }
            if (l16 == 0) {
                int rr = rbase + mb * 16 + quad * 4 + r;
                p_hnall[rr * NSLOT + slot] = v1;
                p_mbel[rr * NSLOT + slot] = v2;
            }
        }
    }
}

// ---------------------------------------------------------------------------
// Kernel 4: per-row loss + per-block sums.
// hn = (mbel > hp - margin) ? mbel : hn_all   (hn_cand == hn_all identity)
// ---------------------------------------------------------------------------
__global__ __launch_bounds__(256) void k_rowloss(
    const float* __restrict__ hp, const float* __restrict__ p_hnall,
    const float* __restrict__ p_mbel, const int* __restrict__ labels,
    float* __restrict__ bsum, float* __restrict__ bcnt)
{
    int i = blockIdx.x * blockDim.x + threadIdx.x;
    float hn_all = -BIGF, mb = -BIGF;
    #pragma unroll
    for (int s = 0; s < NSLOT; ++s) {
        hn_all = fmaxf(hn_all, p_hnall[i * NSLOT + s]);
        mb = fmaxf(mb, p_mbel[i * NSLOT + s]);
    }
    float hpv = hp[i];
    bool valid = (labels[i] == 1) && (hpv < 1e8f) && (hn_all > -1e8f);
    float hn = (mb > hpv - 0.5f) ? mb : hn_all;
    float base = fmaxf(hn - hpv + 0.5f, 0.f);
    float wgt = (hpv < 0.6f || hn > 0.3f) ? 2.f : 1.f;
    float loss = base * wgt + 0.5f * (1.f - hpv) + 0.5f * fmaxf(hn + 0.2f, 0.f);
    float lsum = valid ? loss : 0.f;
    float lcnt = valid ? 1.f : 0.f;
    #pragma unroll
    for (int off = 32; off >= 1; off >>= 1) {
        lsum += __shfl_xor(lsum, off, 64);
        lcnt += __shfl_xor(lcnt, off, 64);
    }
    __shared__ float rs[4], rc[4];
    int wv = threadIdx.x >> 6, lane = threadIdx.x & 63;
    if (lane == 0) { rs[wv] = lsum; rc[wv] = lcnt; }
    __syncthreads();
    if (threadIdx.x == 0) {
        bsum[blockIdx.x] = rs[0] + rs[1] + rs[2] + rs[3];
        bcnt[blockIdx.x] = rc[0] + rc[1] + rc[2] + rc[3];
    }
}

// ---------------------------------------------------------------------------
// Kernel 5: final scalar. nb <= 64 partials.
// ---------------------------------------------------------------------------
__global__ __launch_bounds__(64) void k_final(
    const float* __restrict__ bsum, const float* __restrict__ bcnt,
    float* __restrict__ out, int nb)
{
    int t = threadIdx.x;
    float s = 0.f, c = 0.f;
    if (t < nb) { s = bsum[t]; c = bcnt[t]; }
    #pragma unroll
    for (int off = 32; off >= 1; off >>= 1) {
        s += __shfl_xor(s, off, 64);
        c += __shfl_xor(c, off, 64);
    }
    if (t == 0) out[0] = (c > 0.f) ? s / fmaxf(c, 1.f) : 0.f;
}

extern "C" void kernel_launch(void* const* d_in, const int* in_sizes, int n_in,
                              void* d_out, int out_size, void* d_ws, size_t ws_size,
                              hipStream_t stream)
{
    const float* emb = (const float*)d_in[0];
    const int* labels = (const int*)d_in[1];
    const int* pids = (const int*)d_in[2];
    float* out = (float*)d_out;
    int N = in_sizes[1];          // 8192
    int D = in_sizes[0] / N;      // 256

    char* ws = (char*)d_ws;
    unsigned short* normed = (unsigned short*)ws;  ws += (size_t)N * D * 2;  // 4 MB bf16
    int* gpid = (int*)ws;                          ws += (size_t)N * 4;
    float* hp = (float*)ws;                        ws += (size_t)N * 4;
    float* p_hnall = (float*)ws;                   ws += (size_t)N * NSLOT * 4;
    float* p_mbel = (float*)ws;                    ws += (size_t)N * NSLOT * 4;
    float* bsum = (float*)ws;                      ws += 64 * 4;
    float* bcnt = (float*)ws;                      ws += 64 * 4;

    k_normalize<<<N, D, 0, stream>>>(emb, labels, pids, normed, gpid, hp, D);
    k_hp_pid<<<256, 256, 0, stream>>>(normed, labels, pids, hp, N, D);
    k_pass2<<<dim3(N / 64, COLSPLIT), 256, 0, stream>>>(normed, pids, gpid, hp,
                                                        p_hnall, p_mbel, N, D);
    int rb = N / 256;  // 32
    k_rowloss<<<rb, 256, 0, stream>>>(hp, p_hnall, p_mbel, labels, bsum, bcnt);
    k_final<<<1, 64, 0, stream>>>(bsum, bcnt, out, rb);
}

// Round 3
// 170.821 us; speedup vs baseline: 1.4340x; 1.4027x over previous
//
#include <hip/hip_runtime.h>
#include <hip/hip_bf16.h>
#include <stdint.h>

typedef __attribute__((ext_vector_type(8))) short short8;
typedef __attribute__((ext_vector_type(4))) float f32x4;

#define BIGF 1e9f
#define NSLOT 64                 // col tiles = N/128

__device__ inline float blo(unsigned int u) {
    union { unsigned int i; float f; } v; v.i = u << 16; return v.f;
}
__device__ inline float bhi(unsigned int u) {
    union { unsigned int i; float f; } v; v.i = u & 0xffff0000u; return v.f;
}
__device__ inline unsigned int fkey(float s) {   // order-preserving uint encode
    unsigned int b = __float_as_uint(s);
    return (b & 0x80000000u) ? ~b : (b | 0x80000000u);
}
__device__ inline float funkey(unsigned int k) {
    unsigned int b = (k & 0x80000000u) ? (k & 0x7fffffffu) : ~k;
    return __uint_as_float(b);
}
__device__ inline void async16(const unsigned short* g, unsigned short* l) {
    __builtin_amdgcn_global_load_lds(
        (const __attribute__((address_space(1))) void*)g,
        (__attribute__((address_space(3))) void*)l, 16, 0, 0);
}

// ---------------------------------------------------------------------------
// Kernel 1: L2-normalize rows (fp32), emit bf16 + gpid, init hp sentinel.
// ---------------------------------------------------------------------------
__global__ __launch_bounds__(256) void k_normalize(
    const float* __restrict__ emb, const int* __restrict__ labels,
    const int* __restrict__ pids, unsigned short* __restrict__ normed,
    int* __restrict__ gpid, float* __restrict__ hp_init, int D)
{
    int row = blockIdx.x;
    int t = threadIdx.x;
    float x = emb[(size_t)row * D + t];
    float ss = x * x;
    #pragma unroll
    for (int off = 32; off >= 1; off >>= 1) ss += __shfl_xor(ss, off, 64);
    __shared__ float red[4];
    int wave = t >> 6, lane = t & 63;
    if (lane == 0) red[wave] = ss;
    __syncthreads();
    float total = red[0] + red[1] + red[2] + red[3];
    float norm = fmaxf(sqrtf(total), 1e-12f);
    float v = x / norm;
    __hip_bfloat16 h = __float2bfloat16(v);
    normed[(size_t)row * D + t] = *reinterpret_cast<unsigned short*>(&h);
    if (t == 0) {
        gpid[row] = (labels[row] == 1) ? pids[row] : -1;
        hp_init[row] = BIGF;
    }
}

// ---------------------------------------------------------------------------
// Kernel 2: hardest positive via per-pid groups (~16 genuine per pid).
// ---------------------------------------------------------------------------
__global__ __launch_bounds__(256) void k_hp_pid(
    const unsigned short* __restrict__ normed, const int* __restrict__ labels,
    const int* __restrict__ pids, float* __restrict__ hp_out, int N, int D)
{
    __shared__ int list[512];
    __shared__ unsigned int hp_loc[512];
    __shared__ int cnt;
    int p = blockIdx.x;
    int t = threadIdx.x;
    if (t == 0) cnt = 0;
    __syncthreads();
    for (int j = t; j < N; j += 256)
        if (pids[j] == p && labels[j] == 1) {
            int idx = atomicAdd(&cnt, 1);
            if (idx < 512) list[idx] = j;
        }
    __syncthreads();
    int M = min(cnt, 512);
    for (int s = t; s < M; s += 256) hp_loc[s] = 0xFFFFFFFFu;
    __syncthreads();
    for (int pr = t; pr < M * M; pr += 256) {
        int i = pr / M, j = pr % M;
        if (i == j) continue;
        const uint4* ap = (const uint4*)(normed + (size_t)list[i] * D);
        const uint4* bp = (const uint4*)(normed + (size_t)list[j] * D);
        float s = 0.f;
        #pragma unroll 4
        for (int k = 0; k < D / 8; ++k) {
            uint4 a = ap[k], b = bp[k];
            s += blo(a.x) * blo(b.x) + bhi(a.x) * bhi(b.x);
            s += blo(a.y) * blo(b.y) + bhi(a.y) * bhi(b.y);
            s += blo(a.z) * blo(b.z) + bhi(a.z) * bhi(b.z);
            s += blo(a.w) * blo(b.w) + bhi(a.w) * bhi(b.w);
        }
        atomicMin(&hp_loc[i], fkey(s));
    }
    __syncthreads();
    for (int s = t; s < M; s += 256) {
        unsigned int key = hp_loc[s];
        hp_out[list[s]] = (key == 0xFFFFFFFFu) ? BIGF : funkey(key);
    }
}

// ---------------------------------------------------------------------------
// Kernel 3: m97-structure MFMA pass. 128x128 tile/block, K=256 as 8 BK=32
// steps, double-buffered LDS staged via global_load_lds width=16.
// Per row: hn_all = max sim over negatives; mbel = max over negs < hp.
// grid (ct=N/128, rt=N/128); block 256 = 4 waves 2x2 (wr rows, wc cols).
// ---------------------------------------------------------------------------
__global__ __launch_bounds__(256) void k_pass2(
    const unsigned short* __restrict__ normed, const int* __restrict__ pids,
    const int* __restrict__ gpid, const float* __restrict__ hp,
    float* __restrict__ p_hnall, float* __restrict__ p_mbel, int N)
{
    __shared__ unsigned short As[2][128 * 32];
    __shared__ unsigned short Bs[2][128 * 32];
    __shared__ float hp_s[128];
    __shared__ int pid_s[128], gpc_s[128];
    __shared__ unsigned int red1[128], red2[128];

    const int t = threadIdx.x;
    const int lane = t & 63;
    const int w = t >> 6;
    const int wr = w & 1, wc = w >> 1;
    const int quad = lane >> 4, l16 = lane & 15;
    const int ct = blockIdx.x, rt = blockIdx.y;
    const int rbase = rt * 128, cbase = ct * 128;

    // stage mask scalars + init reduction arrays (covered by first barrier)
    if (t < 128) {
        hp_s[t] = hp[rbase + t];
        pid_s[t] = pids[rbase + t];
        gpc_s[t] = gpid[cbase + t];
        red1[t] = 0u;
        red2[t] = 0u;
    }

    // per-thread staging addresses: row = t>>2, 16B chunk = t&3
    const int srow = t >> 2, schunk = (t & 3) << 3;        // ushort offset
    const unsigned short* gA = normed + ((size_t)(rbase + srow) << 8) + schunk;
    const unsigned short* gB = normed + ((size_t)(cbase + srow) << 8) + schunk;

    // prefetch kb=0
    async16(gA,              &As[0][t * 8]);
    async16(gA + (64 << 8),  &As[0][2048 + t * 8]);
    async16(gB,              &Bs[0][t * 8]);
    async16(gB + (64 << 8),  &Bs[0][2048 + t * 8]);

    f32x4 acc[4][4];
    #pragma unroll
    for (int mt = 0; mt < 4; ++mt)
        #pragma unroll
        for (int nt = 0; nt < 4; ++nt)
            acc[mt][nt] = (f32x4){0.f, 0.f, 0.f, 0.f};

    const int aoff = (wr * 64 + l16) * 32 + quad * 8;      // + mt*16*32
    const int boff = (wc * 64 + l16) * 32 + quad * 8;

    for (int kb = 0; kb < 8; ++kb) {
        __syncthreads();                    // buf[kb&1] ready (vmcnt drained)
        int cur = kb & 1;
        if (kb < 7) {
            int nxt = cur ^ 1;
            int ko = (kb + 1) << 5;
            async16(gA + ko,             &As[nxt][t * 8]);
            async16(gA + ko + (64 << 8), &As[nxt][2048 + t * 8]);
            async16(gB + ko,             &Bs[nxt][t * 8]);
            async16(gB + ko + (64 << 8), &Bs[nxt][2048 + t * 8]);
        }
        short8 af[4], bf[4];
        #pragma unroll
        for (int mt = 0; mt < 4; ++mt)
            af[mt] = *reinterpret_cast<const short8*>(&As[cur][aoff + mt * 512]);
        #pragma unroll
        for (int nt = 0; nt < 4; ++nt)
            bf[nt] = *reinterpret_cast<const short8*>(&Bs[cur][boff + nt * 512]);
        #pragma unroll
        for (int mt = 0; mt < 4; ++mt)
            #pragma unroll
            for (int nt = 0; nt < 4; ++nt)
                acc[mt][nt] = __builtin_amdgcn_mfma_f32_16x16x32_bf16(
                    af[mt], bf[nt], acc[mt][nt], 0, 0, 0);
    }

    // epilogue: masked maxima. C layout: row = mt*16+quad*4+r, col = nt*16+l16
    int gp[4];
    #pragma unroll
    for (int nt = 0; nt < 4; ++nt) gp[nt] = gpc_s[wc * 64 + nt * 16 + l16];
    #pragma unroll
    for (int mt = 0; mt < 4; ++mt) {
        #pragma unroll
        for (int r = 0; r < 4; ++r) {
            int rl = wr * 64 + mt * 16 + quad * 4 + r;
            int prow = pid_s[rl];
            float hprow = hp_s[rl];
            float v1 = -BIGF, v2 = -BIGF;
            #pragma unroll
            for (int nt = 0; nt < 4; ++nt) {
                float s = acc[mt][nt][r];
                float tt = (prow != gp[nt]) ? s : -BIGF;
                v1 = fmaxf(v1, tt);
                float t2 = (tt < hprow) ? tt : -BIGF;
                v2 = fmaxf(v2, t2);
            }
            #pragma unroll
            for (int off = 8; off >= 1; off >>= 1) {
                v1 = fmaxf(v1, __shfl_xor(v1, off, 64));
                v2 = fmaxf(v2, __shfl_xor(v2, off, 64));
            }
            if (l16 == 0) {
                atomicMax(&red1[rl], fkey(v1));
                atomicMax(&red2[rl], fkey(v2));
            }
        }
    }
    __syncthreads();
    if (t < 128) {
        int row = rbase + t;
        p_hnall[(size_t)row * NSLOT + ct] = funkey(red1[t]);
        p_mbel[(size_t)row * NSLOT + ct] = funkey(red2[t]);
    }
}

// ---------------------------------------------------------------------------
// Kernel 4: per-row loss + per-block sums.
// hn = (mbel > hp - margin) ? mbel : hn_all   (hn_cand == hn_all identity)
// ---------------------------------------------------------------------------
__global__ __launch_bounds__(256) void k_rowloss(
    const float* __restrict__ hp, const float* __restrict__ p_hnall,
    const float* __restrict__ p_mbel, const int* __restrict__ labels,
    float* __restrict__ bsum, float* __restrict__ bcnt)
{
    int i = blockIdx.x * blockDim.x + threadIdx.x;
    float hn_all = -BIGF, mb = -BIGF;
    const float4* ph = (const float4*)(p_hnall + (size_t)i * NSLOT);
    const float4* pm = (const float4*)(p_mbel + (size_t)i * NSLOT);
    #pragma unroll
    for (int s = 0; s < NSLOT / 4; ++s) {
        float4 a = ph[s], b = pm[s];
        hn_all = fmaxf(hn_all, fmaxf(fmaxf(a.x, a.y), fmaxf(a.z, a.w)));
        mb = fmaxf(mb, fmaxf(fmaxf(b.x, b.y), fmaxf(b.z, b.w)));
    }
    float hpv = hp[i];
    bool valid = (labels[i] == 1) && (hpv < 1e8f) && (hn_all > -1e8f);
    float hn = (mb > hpv - 0.5f) ? mb : hn_all;
    float base = fmaxf(hn - hpv + 0.5f, 0.f);
    float wgt = (hpv < 0.6f || hn > 0.3f) ? 2.f : 1.f;
    float loss = base * wgt + 0.5f * (1.f - hpv) + 0.5f * fmaxf(hn + 0.2f, 0.f);
    float lsum = valid ? loss : 0.f;
    float lcnt = valid ? 1.f : 0.f;
    #pragma unroll
    for (int off = 32; off >= 1; off >>= 1) {
        lsum += __shfl_xor(lsum, off, 64);
        lcnt += __shfl_xor(lcnt, off, 64);
    }
    __shared__ float rs[4], rc[4];
    int wv = threadIdx.x >> 6, lane = threadIdx.x & 63;
    if (lane == 0) { rs[wv] = lsum; rc[wv] = lcnt; }
    __syncthreads();
    if (threadIdx.x == 0) {
        bsum[blockIdx.x] = rs[0] + rs[1] + rs[2] + rs[3];
        bcnt[blockIdx.x] = rc[0] + rc[1] + rc[2] + rc[3];
    }
}

// ---------------------------------------------------------------------------
// Kernel 5: final scalar.
// ---------------------------------------------------------------------------
__global__ __launch_bounds__(64) void k_final(
    const float* __restrict__ bsum, const float* __restrict__ bcnt,
    float* __restrict__ out, int nb)
{
    int t = threadIdx.x;
    float s = 0.f, c = 0.f;
    if (t < nb) { s = bsum[t]; c = bcnt[t]; }
    #pragma unroll
    for (int off = 32; off >= 1; off >>= 1) {
        s += __shfl_xor(s, off, 64);
        c += __shfl_xor(c, off, 64);
    }
    if (t == 0) out[0] = (c > 0.f) ? s / fmaxf(c, 1.f) : 0.f;
}

extern "C" void kernel_launch(void* const* d_in, const int* in_sizes, int n_in,
                              void* d_out, int out_size, void* d_ws, size_t ws_size,
                              hipStream_t stream)
{
    const float* emb = (const float*)d_in[0];
    const int* labels = (const int*)d_in[1];
    const int* pids = (const int*)d_in[2];
    float* out = (float*)d_out;
    int N = in_sizes[1];          // 8192
    int D = in_sizes[0] / N;      // 256

    char* ws = (char*)d_ws;
    unsigned short* normed = (unsigned short*)ws;  ws += (size_t)N * D * 2;  // 4 MB bf16
    int* gpid = (int*)ws;                          ws += (size_t)N * 4;
    float* hp = (float*)ws;                        ws += (size_t)N * 4;
    float* p_hnall = (float*)ws;                   ws += (size_t)N * NSLOT * 4;
    float* p_mbel = (float*)ws;                    ws += (size_t)N * NSLOT * 4;
    float* bsum = (float*)ws;                      ws += 64 * 4;
    float* bcnt = (float*)ws;                      ws += 64 * 4;

    k_normalize<<<N, D, 0, stream>>>(emb, labels, pids, normed, gpid, hp, D);
    k_hp_pid<<<256, 256, 0, stream>>>(normed, labels, pids, hp, N, D);
    k_pass2<<<dim3(N / 128, N / 128), 256, 0, stream>>>(normed, pids, gpid, hp,
                                                        p_hnall, p_mbel, N);
    int rb = N / 256;  // 32
    k_rowloss<<<rb, 256, 0, stream>>>(hp, p_hnall, p_mbel, labels, bsum, bcnt);
    k_final<<<1, 64, 0, stream>>>(bsum, bcnt, out, rb);
}

// Round 4
// 164.310 us; speedup vs baseline: 1.4909x; 1.0396x over previous
//
#include <hip/hip_runtime.h>
#include <hip/hip_bf16.h>
#include <stdint.h>

typedef __attribute__((ext_vector_type(8))) short short8;
typedef __attribute__((ext_vector_type(4))) float f32x4;

#define BIGF 1e9f
#define NSLOT 64                 // col tiles = N/128

__device__ inline float blo(unsigned int u) {
    union { unsigned int i; float f; } v; v.i = u << 16; return v.f;
}
__device__ inline float bhi(unsigned int u) {
    union { unsigned int i; float f; } v; v.i = u & 0xffff0000u; return v.f;
}
__device__ inline unsigned int fkey(float s) {   // order-preserving uint encode
    unsigned int b = __float_as_uint(s);
    return (b & 0x80000000u) ? ~b : (b | 0x80000000u);
}
__device__ inline float funkey(unsigned int k) {
    unsigned int b = (k & 0x80000000u) ? (k & 0x7fffffffu) : ~k;
    return __uint_as_float(b);
}
__device__ inline void async16(const unsigned short* g, unsigned short* l) {
    __builtin_amdgcn_global_load_lds(
        (const __attribute__((address_space(1))) void*)g,
        (__attribute__((address_space(3))) void*)l, 16, 0, 0);
}
__device__ inline unsigned short f2b(float x) {
    __hip_bfloat16 h = __float2bfloat16(x);
    return *reinterpret_cast<unsigned short*>(&h);
}

// ---------------------------------------------------------------------------
// Kernel 1: L2-normalize rows (fp32), emit bf16 + gpid, init hp sentinel.
// One wave per row: float4 loads, wave-local reduce, no LDS/syncthreads.
// ---------------------------------------------------------------------------
__global__ __launch_bounds__(256) void k_normalize(
    const float* __restrict__ emb, const int* __restrict__ labels,
    const int* __restrict__ pids, unsigned short* __restrict__ normed,
    int* __restrict__ gpid, float* __restrict__ hp_init)
{
    int w = threadIdx.x >> 6, lane = threadIdx.x & 63;
    int row = blockIdx.x * 4 + w;
    const float4* src = (const float4*)(emb + ((size_t)row << 8));
    float4 x = src[lane];
    float ss = x.x * x.x + x.y * x.y + x.z * x.z + x.w * x.w;
    #pragma unroll
    for (int off = 32; off >= 1; off >>= 1) ss += __shfl_xor(ss, off, 64);
    float inv = 1.0f / fmaxf(sqrtf(ss), 1e-12f);
    ushort4 o;
    o.x = f2b(x.x * inv); o.y = f2b(x.y * inv);
    o.z = f2b(x.z * inv); o.w = f2b(x.w * inv);
    ((ushort4*)(normed + ((size_t)row << 8)))[lane] = o;
    if (lane == 0) {
        gpid[row] = (labels[row] == 1) ? pids[row] : -1;
        hp_init[row] = BIGF;
    }
}

// ---------------------------------------------------------------------------
// Kernel 2: hardest positive via per-pid groups (~16 genuine per pid).
// ---------------------------------------------------------------------------
__global__ __launch_bounds__(256) void k_hp_pid(
    const unsigned short* __restrict__ normed, const int* __restrict__ labels,
    const int* __restrict__ pids, float* __restrict__ hp_out, int N, int D)
{
    __shared__ int list[512];
    __shared__ unsigned int hp_loc[512];
    __shared__ int cnt;
    int p = blockIdx.x;
    int t = threadIdx.x;
    if (t == 0) cnt = 0;
    __syncthreads();
    for (int j = t; j < N; j += 256)
        if (pids[j] == p && labels[j] == 1) {
            int idx = atomicAdd(&cnt, 1);
            if (idx < 512) list[idx] = j;
        }
    __syncthreads();
    int M = min(cnt, 512);
    for (int s = t; s < M; s += 256) hp_loc[s] = 0xFFFFFFFFu;
    __syncthreads();
    for (int pr = t; pr < M * M; pr += 256) {
        int i = pr / M, j = pr % M;
        if (i == j) continue;
        const uint4* ap = (const uint4*)(normed + (size_t)list[i] * D);
        const uint4* bp = (const uint4*)(normed + (size_t)list[j] * D);
        float s = 0.f;
        #pragma unroll 4
        for (int k = 0; k < D / 8; ++k) {
            uint4 a = ap[k], b = bp[k];
            s += blo(a.x) * blo(b.x) + bhi(a.x) * bhi(b.x);
            s += blo(a.y) * blo(b.y) + bhi(a.y) * bhi(b.y);
            s += blo(a.z) * blo(b.z) + bhi(a.z) * bhi(b.z);
            s += blo(a.w) * blo(b.w) + bhi(a.w) * bhi(b.w);
        }
        atomicMin(&hp_loc[i], fkey(s));
    }
    __syncthreads();
    for (int s = t; s < M; s += 256) {
        unsigned int key = hp_loc[s];
        hp_out[list[s]] = (key == 0xFFFFFFFFu) ? BIGF : funkey(key);
    }
}

// ---------------------------------------------------------------------------
// Kernel 3: m97-structure MFMA pass with XOR-swizzled LDS chunk placement
// (kills the 8-way ds_read_b128 bank conflicts; swizzle lives in the global
// source address so global_load_lds lane-contiguity is preserved).
// 128x128 tile/block, K=256 as 8 BK=32 double-buffered steps.
// Partials written transposed: p[ct*N + row] (coalesced 512B per block).
// ---------------------------------------------------------------------------
__global__ __launch_bounds__(256) void k_pass2(
    const unsigned short* __restrict__ normed, const int* __restrict__ pids,
    const int* __restrict__ gpid, const float* __restrict__ hp,
    float* __restrict__ p_hnall, float* __restrict__ p_mbel, int N)
{
    __shared__ unsigned short As[2][128 * 32];
    __shared__ unsigned short Bs[2][128 * 32];
    __shared__ float hp_s[128];
    __shared__ int pid_s[128], gpc_s[128];
    __shared__ unsigned int red1[128], red2[128];

    const int t = threadIdx.x;
    const int lane = t & 63;
    const int w = t >> 6;
    const int wr = w & 1, wc = w >> 1;
    const int quad = lane >> 4, l16 = lane & 15;
    const int ct = blockIdx.x, rt = blockIdx.y;
    const int rbase = rt * 128, cbase = ct * 128;

    if (t < 128) {
        hp_s[t] = hp[rbase + t];
        pid_s[t] = pids[rbase + t];
        gpc_s[t] = gpid[cbase + t];
        red1[t] = 0u;
        red2[t] = 0u;
    }

    // staging: LDS chunk cid in {t, t+256}; row = cid>>2, pos = cid&3.
    // LDS pos holds global 16B chunk c = pos ^ ((row>>1)&3).
    const int r0 = t >> 2, p0 = t & 3;
    const int c0 = p0 ^ ((r0 >> 1) & 3);      // same swizzle for row r0+64
    const unsigned short* gA0 = normed + ((size_t)(rbase + r0) << 8) + c0 * 8;
    const unsigned short* gA1 = normed + ((size_t)(rbase + r0 + 64) << 8) + c0 * 8;
    const unsigned short* gB0 = normed + ((size_t)(cbase + r0) << 8) + c0 * 8;
    const unsigned short* gB1 = normed + ((size_t)(cbase + r0 + 64) << 8) + c0 * 8;

    // prefetch kb=0
    async16(gA0, &As[0][t * 8]);
    async16(gA1, &As[0][2048 + t * 8]);
    async16(gB0, &Bs[0][t * 8]);
    async16(gB1, &Bs[0][2048 + t * 8]);

    f32x4 acc[4][4];
    #pragma unroll
    for (int mt = 0; mt < 4; ++mt)
        #pragma unroll
        for (int nt = 0; nt < 4; ++nt)
            acc[mt][nt] = (f32x4){0.f, 0.f, 0.f, 0.f};

    // fragment read: row = wr*64 + mt*16 + l16 -> swizzle bits from l16 only
    const int sw = (l16 >> 1) & 3;
    const int aoff = (wr * 64 + l16) * 32 + (quad ^ sw) * 8;   // + mt*512
    const int boff = (wc * 64 + l16) * 32 + (quad ^ sw) * 8;   // + nt*512

    for (int kb = 0; kb < 8; ++kb) {
        __syncthreads();                    // buf[kb&1] ready (vmcnt drained)
        int cur = kb & 1;
        if (kb < 7) {
            int nxt = cur ^ 1;
            int ko = (kb + 1) << 5;
            async16(gA0 + ko, &As[nxt][t * 8]);
            async16(gA1 + ko, &As[nxt][2048 + t * 8]);
            async16(gB0 + ko, &Bs[nxt][t * 8]);
            async16(gB1 + ko, &Bs[nxt][2048 + t * 8]);
        }
        short8 af[4], bf[4];
        #pragma unroll
        for (int mt = 0; mt < 4; ++mt)
            af[mt] = *reinterpret_cast<const short8*>(&As[cur][aoff + mt * 512]);
        #pragma unroll
        for (int nt = 0; nt < 4; ++nt)
            bf[nt] = *reinterpret_cast<const short8*>(&Bs[cur][boff + nt * 512]);
        #pragma unroll
        for (int mt = 0; mt < 4; ++mt)
            #pragma unroll
            for (int nt = 0; nt < 4; ++nt)
                acc[mt][nt] = __builtin_amdgcn_mfma_f32_16x16x32_bf16(
                    af[mt], bf[nt], acc[mt][nt], 0, 0, 0);
    }

    // epilogue: masked maxima. C layout: row = mt*16+quad*4+r, col = nt*16+l16
    int gp[4];
    #pragma unroll
    for (int nt = 0; nt < 4; ++nt) gp[nt] = gpc_s[wc * 64 + nt * 16 + l16];
    #pragma unroll
    for (int mt = 0; mt < 4; ++mt) {
        #pragma unroll
        for (int r = 0; r < 4; ++r) {
            int rl = wr * 64 + mt * 16 + quad * 4 + r;
            int prow = pid_s[rl];
            float hprow = hp_s[rl];
            float v1 = -BIGF, v2 = -BIGF;
            #pragma unroll
            for (int nt = 0; nt < 4; ++nt) {
                float s = acc[mt][nt][r];
                float tt = (prow != gp[nt]) ? s : -BIGF;
                v1 = fmaxf(v1, tt);
                float t2 = (tt < hprow) ? tt : -BIGF;
                v2 = fmaxf(v2, t2);
            }
            #pragma unroll
            for (int off = 8; off >= 1; off >>= 1) {
                v1 = fmaxf(v1, __shfl_xor(v1, off, 64));
                v2 = fmaxf(v2, __shfl_xor(v2, off, 64));
            }
            if (l16 == 0) {
                atomicMax(&red1[rl], fkey(v1));
                atomicMax(&red2[rl], fkey(v2));
            }
        }
    }
    __syncthreads();
    if (t < 128) {
        p_hnall[(size_t)ct * N + rbase + t] = funkey(red1[t]);
        p_mbel[(size_t)ct * N + rbase + t] = funkey(red2[t]);
    }
}

// ---------------------------------------------------------------------------
// Kernel 4: per-row loss + grid reduce + fused final (last-block pattern).
// Transposed partials -> fully coalesced reads.
// hn = (mbel > hp - margin) ? mbel : hn_all   (hn_cand == hn_all identity)
// ---------------------------------------------------------------------------
__global__ __launch_bounds__(256) void k_rowloss(
    const float* __restrict__ hp, const float* __restrict__ p_hnall,
    const float* __restrict__ p_mbel, const int* __restrict__ labels,
    float* __restrict__ gred, int* __restrict__ done,
    float* __restrict__ out, int N)
{
    int i = blockIdx.x * 256 + threadIdx.x;
    float hn_all = -BIGF, mb = -BIGF;
    #pragma unroll 8
    for (int s = 0; s < NSLOT; ++s) {
        hn_all = fmaxf(hn_all, p_hnall[(size_t)s * N + i]);
        mb = fmaxf(mb, p_mbel[(size_t)s * N + i]);
    }
    float hpv = hp[i];
    bool valid = (labels[i] == 1) && (hpv < 1e8f) && (hn_all > -1e8f);
    float hn = (mb > hpv - 0.5f) ? mb : hn_all;
    float base = fmaxf(hn - hpv + 0.5f, 0.f);
    float wgt = (hpv < 0.6f || hn > 0.3f) ? 2.f : 1.f;
    float loss = base * wgt + 0.5f * (1.f - hpv) + 0.5f * fmaxf(hn + 0.2f, 0.f);
    float lsum = valid ? loss : 0.f;
    float lcnt = valid ? 1.f : 0.f;
    #pragma unroll
    for (int off = 32; off >= 1; off >>= 1) {
        lsum += __shfl_xor(lsum, off, 64);
        lcnt += __shfl_xor(lcnt, off, 64);
    }
    __shared__ float rs[4], rc[4];
    int wv = threadIdx.x >> 6, lane = threadIdx.x & 63;
    if (lane == 0) { rs[wv] = lsum; rc[wv] = lcnt; }
    __syncthreads();
    if (threadIdx.x == 0) {
        atomicAdd(&gred[0], rs[0] + rs[1] + rs[2] + rs[3]);
        atomicAdd(&gred[1], rc[0] + rc[1] + rc[2] + rc[3]);
        __threadfence();
        int old = atomicAdd(done, 1);
        if (old == (int)gridDim.x - 1) {
            float S = atomicAdd(&gred[0], 0.f);
            float C = atomicAdd(&gred[1], 0.f);
            out[0] = (C > 0.f) ? S / fmaxf(C, 1.f) : 0.f;
        }
    }
}

extern "C" void kernel_launch(void* const* d_in, const int* in_sizes, int n_in,
                              void* d_out, int out_size, void* d_ws, size_t ws_size,
                              hipStream_t stream)
{
    const float* emb = (const float*)d_in[0];
    const int* labels = (const int*)d_in[1];
    const int* pids = (const int*)d_in[2];
    float* out = (float*)d_out;
    int N = in_sizes[1];          // 8192
    int D = in_sizes[0] / N;      // 256

    char* ws = (char*)d_ws;
    unsigned short* normed = (unsigned short*)ws;  ws += (size_t)N * D * 2;  // 4 MB bf16
    int* gpid = (int*)ws;                          ws += (size_t)N * 4;
    float* hp = (float*)ws;                        ws += (size_t)N * 4;
    float* p_hnall = (float*)ws;                   ws += (size_t)N * NSLOT * 4;
    float* p_mbel = (float*)ws;                    ws += (size_t)N * NSLOT * 4;
    float* gred = (float*)ws;                      ws += 2 * 4;   // [sum, cnt]
    int* done = (int*)ws;                          ws += 4;

    hipMemsetAsync(gred, 0, 12, stream);   // gred[0], gred[1], done

    k_normalize<<<N / 4, 256, 0, stream>>>(emb, labels, pids, normed, gpid, hp);
    k_hp_pid<<<256, 256, 0, stream>>>(normed, labels, pids, hp, N, D);
    k_pass2<<<dim3(N / 128, N / 128), 256, 0, stream>>>(normed, pids, gpid, hp,
                                                        p_hnall, p_mbel, N);
    k_rowloss<<<N / 256, 256, 0, stream>>>(hp, p_hnall, p_mbel, labels,
                                           gred, done, out, N);
}